// Round 3
// baseline (450.476 us; speedup 1.0000x reference)
//
#include <hip/hip_runtime.h>
#include <stdint.h>

#define DIM 128
#define NPROJ 256
#define TPB 128                    // tokens per block (4 waves x 32)
#define TAU 0.016f                 // refine threshold on |k_proj_f16| (~7 sigma)
#define QCAP 512
#define DEQ 0.004895758348888673f  // sqrt(pi/2)/256

typedef _Float16 f16x8 __attribute__((ext_vector_type(8)));
typedef float f32x4 __attribute__((ext_vector_type(4)));

// ---- prep: S fp32 -> f16 B-fragments, pre-swizzled into MFMA lane order ----
// frag id fid = (c*4 + ks)*2 + f   (c: 32-proj chunk, ks: k-step, f: 16-proj tile)
// lane l holds B[n=p][k=d] els: p = c*32 + f*16 + (l&15), d = ks*32 + (l>>4)*8 + j
__global__ __launch_bounds__(256) void qjl_prep(const float* __restrict__ Sg,
                                                _Float16* __restrict__ ws) {
    int t = blockIdx.x * 256 + threadIdx.x;   // 0..4095
    int lane = t & 63, fid = t >> 6;          // 64 frags
    int f = fid & 1, ks = (fid >> 1) & 3, c = fid >> 3;
    int p = c * 32 + f * 16 + (lane & 15);
    int d0 = ks * 32 + (lane >> 4) * 8;
    const float4* s4 = (const float4*)(Sg + p * DIM + d0);
    float4 a = s4[0], b = s4[1];
    f16x8 h = {(_Float16)a.x, (_Float16)a.y, (_Float16)a.z, (_Float16)a.w,
               (_Float16)b.x, (_Float16)b.y, (_Float16)b.z, (_Float16)b.w};
    *(f16x8*)(ws + (size_t)fid * 512 + lane * 8) = h;
}

__global__ __launch_bounds__(256, 3) void qjl_main(
    const float* __restrict__ qg, const float* __restrict__ kg,
    const float* __restrict__ Sg, const _Float16* __restrict__ ws,
    float* __restrict__ out)
{
    __shared__ float    est_s[TPB];
    __shared__ uint32_t qmeta[QCAP];
    __shared__ float    qdlt[QCAP];
    __shared__ int      qn;

    const int tid = threadIdx.x, lane = tid & 63, wv = tid >> 6;
    const int m = lane & 15, quad = lane >> 4;
    const long tok0 = (long)blockIdx.x * TPB;
    if (tid == 0) qn = 0;
    __syncthreads();

    // ---- B double-buffer: issue chunk-0 loads before the A prologue ----
    f16x8 bb[2][8];
    #pragma unroll
    for (int ks = 0; ks < 4; ++ks) {
        bb[0][ks * 2 + 0] = *(const f16x8*)(ws + (size_t)(0 * 8 + ks * 2 + 0) * 512 + lane * 8);
        bb[0][ks * 2 + 1] = *(const f16x8*)(ws + (size_t)(0 * 8 + ks * 2 + 1) * 512 + lane * 8);
    }

    // ---- A fragments: fp32 -> f16 straight into registers (no LDS) ----
    f16x8 ak[2][4], aq[2][4];
    #pragma unroll
    for (int rb = 0; rb < 2; ++rb) {
        long row = tok0 + wv * 32 + rb * 16 + m;
        const float* kr = kg + row * DIM;
        const float* qr = qg + row * DIM;
        #pragma unroll
        for (int ks = 0; ks < 4; ++ks) {
            int d0 = ks * 32 + quad * 8;
            float4 x = *(const float4*)(kr + d0);
            float4 y = *(const float4*)(kr + d0 + 4);
            ak[rb][ks] = (f16x8){(_Float16)x.x, (_Float16)x.y, (_Float16)x.z, (_Float16)x.w,
                                 (_Float16)y.x, (_Float16)y.y, (_Float16)y.z, (_Float16)y.w};
            float4 u = *(const float4*)(qr + d0);
            float4 v = *(const float4*)(qr + d0 + 4);
            aq[rb][ks] = (f16x8){(_Float16)u.x, (_Float16)u.y, (_Float16)u.z, (_Float16)u.w,
                                 (_Float16)v.x, (_Float16)v.y, (_Float16)v.z, (_Float16)v.w};
        }
    }

    float est[8] = {0.f, 0.f, 0.f, 0.f, 0.f, 0.f, 0.f, 0.f};

    // ---- main loop over 8 proj-chunks, software-pipelined B ----
    #pragma unroll
    for (int c = 0; c < 8; ++c) {
        const int cur = c & 1;
        if (c < 7) {
            #pragma unroll
            for (int ks = 0; ks < 4; ++ks) {
                bb[cur ^ 1][ks * 2 + 0] = *(const f16x8*)(ws + (size_t)((c + 1) * 8 + ks * 2 + 0) * 512 + lane * 8);
                bb[cur ^ 1][ks * 2 + 1] = *(const f16x8*)(ws + (size_t)((c + 1) * 8 + ks * 2 + 1) * 512 + lane * 8);
            }
        }
        #pragma unroll
        for (int rb = 0; rb < 2; ++rb) {
            f32x4 kacc0 = {0,0,0,0}, kacc1 = {0,0,0,0};
            f32x4 qacc0 = {0,0,0,0}, qacc1 = {0,0,0,0};
            #pragma unroll
            for (int ks = 0; ks < 4; ++ks) {
                kacc0 = __builtin_amdgcn_mfma_f32_16x16x32_f16(ak[rb][ks], bb[cur][ks * 2 + 0], kacc0, 0, 0, 0);
                kacc1 = __builtin_amdgcn_mfma_f32_16x16x32_f16(ak[rb][ks], bb[cur][ks * 2 + 1], kacc1, 0, 0, 0);
                qacc0 = __builtin_amdgcn_mfma_f32_16x16x32_f16(aq[rb][ks], bb[cur][ks * 2 + 0], qacc0, 0, 0, 0);
                qacc1 = __builtin_amdgcn_mfma_f32_16x16x32_f16(aq[rb][ks], bb[cur][ks * 2 + 1], qacc1, 0, 0, 0);
            }
            // C layout: col = lane&15 (proj in tile), row = quad*4 + r (token in 16-block)
            #pragma unroll
            for (int r = 0; r < 4; ++r) {
                int tl = wv * 32 + rb * 16 + quad * 4 + r;
                {
                    float kv = kacc0[r], qv = qacc0[r];
                    float sg = (kv > 0.f) ? 1.f : -1.f;
                    est[rb * 4 + r] += qv * sg;
                    if (__builtin_expect(fabsf(kv) < TAU, 0)) {
                        int p = c * 32 + m;
                        int idx = atomicAdd(&qn, 1);
                        if (idx < QCAP) {
                            qmeta[idx] = (uint32_t)tl | ((uint32_t)p << 8) | ((kv > 0.f ? 1u : 0u) << 16);
                            qdlt[idx]  = DEQ * qv * sg;
                        }
                    }
                }
                {
                    float kv = kacc1[r], qv = qacc1[r];
                    float sg = (kv > 0.f) ? 1.f : -1.f;
                    est[rb * 4 + r] += qv * sg;
                    if (__builtin_expect(fabsf(kv) < TAU, 0)) {
                        int p = c * 32 + 16 + m;
                        int idx = atomicAdd(&qn, 1);
                        if (idx < QCAP) {
                            qmeta[idx] = (uint32_t)tl | ((uint32_t)p << 8) | ((kv > 0.f ? 1u : 0u) << 16);
                            qdlt[idx]  = DEQ * qv * sg;
                        }
                    }
                }
            }
        }
    }

    // ---- reduce est over the 16 proj-lanes ----
    #pragma unroll
    for (int rb = 0; rb < 2; ++rb) {
        #pragma unroll
        for (int r = 0; r < 4; ++r) {
            float e = est[rb * 4 + r];
            e += __shfl_xor(e, 1);
            e += __shfl_xor(e, 2);
            e += __shfl_xor(e, 4);
            e += __shfl_xor(e, 8);
            if (m == 0) est_s[wv * 32 + rb * 16 + quad * 4 + r] = DEQ * e;
        }
    }
    __syncthreads();

    // ---- refine: per-THREAD exact fp64 dot for near-zero k_proj candidates ----
    int nc = qn < QCAP ? qn : QCAP;
    for (int i = tid; i < nc; i += 256) {
        uint32_t mm = qmeta[i];
        int tl = mm & 255;
        int p  = (mm >> 8) & 255;
        int sf = (mm >> 16) & 1;
        const float4* kr = (const float4*)(kg + (tok0 + tl) * DIM);
        const float4* sr = (const float4*)(Sg + (long)p * DIM);
        double acc = 0.0;
        #pragma unroll 8
        for (int jj = 0; jj < 32; ++jj) {
            float4 ka = kr[jj], sa = sr[jj];
            acc += (double)ka.x * (double)sa.x + (double)ka.y * (double)sa.y
                 + (double)ka.z * (double)sa.z + (double)ka.w * (double)sa.w;
        }
        int st = (acc > 0.0) ? 1 : 0;
        if (st != sf) atomicAdd(&est_s[tl], -2.f * qdlt[i]);
    }
    __syncthreads();

    if (tid < TPB) out[tok0 + tid] = est_s[tid];
}

extern "C" void kernel_launch(void* const* d_in, const int* in_sizes, int n_in,
                              void* d_out, int out_size, void* d_ws, size_t ws_size,
                              hipStream_t stream) {
    const float* q = (const float*)d_in[0];
    const float* k = (const float*)d_in[1];
    const float* S = (const float*)d_in[2];
    float* out = (float*)d_out;
    _Float16* ws = (_Float16*)d_ws;
    hipLaunchKernelGGL(qjl_prep, dim3(16), dim3(256), 0, stream, S, ws);
    int nblocks = out_size / TPB;   // 262144 / 128 = 2048
    hipLaunchKernelGGL(qjl_main, dim3(nblocks), dim3(256), 0, stream, q, k, S, ws, out);
}

// Round 4
// 385.269 us; speedup vs baseline: 1.1692x; 1.1692x over previous
//
#include <hip/hip_runtime.h>
#include <stdint.h>

#define DIM 128
#define NPROJ 256
#define TPB 128                    // tokens per block (4 waves x 32)
#define TAU 0.016f                 // refine threshold on |k_proj_f16| (~7 sigma)
#define QCAP 512
#define DEQ 0.004895758348888673f  // sqrt(pi/2)/256

typedef _Float16 f16x8 __attribute__((ext_vector_type(8)));
typedef float f32x4 __attribute__((ext_vector_type(4)));

// ---- prep: S fp32 -> f16 B-fragments, pre-swizzled into MFMA lane order ----
// frag id fid = (c*4 + ks)*2 + f   (c: 32-proj chunk, ks: k-step, f: 16-proj tile)
// lane l holds B[n=p][k=d] els: p = c*32 + f*16 + (l&15), d = ks*32 + (l>>4)*8 + j
__global__ __launch_bounds__(256) void qjl_prep(const float* __restrict__ Sg,
                                                _Float16* __restrict__ ws) {
    int t = blockIdx.x * 256 + threadIdx.x;   // 0..4095
    int lane = t & 63, fid = t >> 6;          // 64 frags
    int f = fid & 1, ks = (fid >> 1) & 3, c = fid >> 3;
    int p = c * 32 + f * 16 + (lane & 15);
    int d0 = ks * 32 + (lane >> 4) * 8;
    const float4* s4 = (const float4*)(Sg + p * DIM + d0);
    float4 a = s4[0], b = s4[1];
    f16x8 h = {(_Float16)a.x, (_Float16)a.y, (_Float16)a.z, (_Float16)a.w,
               (_Float16)b.x, (_Float16)b.y, (_Float16)b.z, (_Float16)b.w};
    *(f16x8*)(ws + (size_t)fid * 512 + lane * 8) = h;
}

// load chunk C's 8 B-fragments into named buffer (all indices compile-time)
#define LOADB(buf, C)                                                                  \
    {                                                                                  \
        _Pragma("unroll")                                                              \
        for (int ks = 0; ks < 4; ++ks) {                                               \
            buf[ks * 2 + 0] = *(const f16x8*)(ws + (size_t)((C) * 8 + ks * 2 + 0) * 512 + lane * 8); \
            buf[ks * 2 + 1] = *(const f16x8*)(ws + (size_t)((C) * 8 + ks * 2 + 1) * 512 + lane * 8); \
        }                                                                              \
    }

#define DO_CHUNK(C, buf)                                                               \
    {                                                                                  \
        _Pragma("unroll")                                                              \
        for (int rb = 0; rb < 2; ++rb) {                                               \
            f32x4 kacc0 = {0, 0, 0, 0}, kacc1 = {0, 0, 0, 0};                          \
            f32x4 qacc0 = {0, 0, 0, 0}, qacc1 = {0, 0, 0, 0};                          \
            _Pragma("unroll")                                                          \
            for (int ks = 0; ks < 4; ++ks) {                                           \
                kacc0 = __builtin_amdgcn_mfma_f32_16x16x32_f16(ak[rb][ks], buf[ks * 2 + 0], kacc0, 0, 0, 0); \
                kacc1 = __builtin_amdgcn_mfma_f32_16x16x32_f16(ak[rb][ks], buf[ks * 2 + 1], kacc1, 0, 0, 0); \
                qacc0 = __builtin_amdgcn_mfma_f32_16x16x32_f16(aq[rb][ks], buf[ks * 2 + 0], qacc0, 0, 0, 0); \
                qacc1 = __builtin_amdgcn_mfma_f32_16x16x32_f16(aq[rb][ks], buf[ks * 2 + 1], qacc1, 0, 0, 0); \
            }                                                                          \
            _Pragma("unroll")                                                          \
            for (int r = 0; r < 4; ++r) {                                              \
                int tl = wv * 32 + rb * 16 + quad * 4 + r;                             \
                {                                                                      \
                    float kv = kacc0[r], qv = qacc0[r];                                \
                    float sg = (kv > 0.f) ? 1.f : -1.f;                                \
                    est[rb * 4 + r] += qv * sg;                                        \
                    if (__builtin_expect(fabsf(kv) < TAU, 0)) {                        \
                        int p = (C) * 32 + m;                                          \
                        int idx = atomicAdd(&qn, 1);                                   \
                        if (idx < QCAP) {                                              \
                            qmeta[idx] = (uint32_t)tl | ((uint32_t)p << 8) | ((kv > 0.f ? 1u : 0u) << 16); \
                            qdlt[idx]  = DEQ * qv * sg;                                \
                        }                                                              \
                    }                                                                  \
                }                                                                      \
                {                                                                      \
                    float kv = kacc1[r], qv = qacc1[r];                                \
                    float sg = (kv > 0.f) ? 1.f : -1.f;                                \
                    est[rb * 4 + r] += qv * sg;                                        \
                    if (__builtin_expect(fabsf(kv) < TAU, 0)) {                        \
                        int p = (C) * 32 + 16 + m;                                     \
                        int idx = atomicAdd(&qn, 1);                                   \
                        if (idx < QCAP) {                                              \
                            qmeta[idx] = (uint32_t)tl | ((uint32_t)p << 8) | ((kv > 0.f ? 1u : 0u) << 16); \
                            qdlt[idx]  = DEQ * qv * sg;                                \
                        }                                                              \
                    }                                                                  \
                }                                                                      \
            }                                                                          \
        }                                                                              \
    }

__global__ __launch_bounds__(256, 2) void qjl_main(
    const float* __restrict__ qg, const float* __restrict__ kg,
    const float* __restrict__ Sg, const _Float16* __restrict__ ws,
    float* __restrict__ out)
{
    __shared__ float    est_s[TPB];
    __shared__ uint32_t qmeta[QCAP];
    __shared__ float    qdlt[QCAP];
    __shared__ int      qn;

    const int tid = threadIdx.x, lane = tid & 63, wv = tid >> 6;
    const int m = lane & 15, quad = lane >> 4;
    const long tok0 = (long)blockIdx.x * TPB;
    if (tid == 0) qn = 0;
    __syncthreads();

    // ---- named double buffers for B (registers, constant indices only) ----
    f16x8 bA[8], bB[8];
    LOADB(bA, 0);

    // ---- A fragments: fp32 -> f16 straight into registers (no LDS) ----
    f16x8 ak[2][4], aq[2][4];
    #pragma unroll
    for (int rb = 0; rb < 2; ++rb) {
        long row = tok0 + wv * 32 + rb * 16 + m;
        const float* kr = kg + row * DIM;
        const float* qr = qg + row * DIM;
        #pragma unroll
        for (int ks = 0; ks < 4; ++ks) {
            int d0 = ks * 32 + quad * 8;
            float4 x = *(const float4*)(kr + d0);
            float4 y = *(const float4*)(kr + d0 + 4);
            ak[rb][ks] = (f16x8){(_Float16)x.x, (_Float16)x.y, (_Float16)x.z, (_Float16)x.w,
                                 (_Float16)y.x, (_Float16)y.y, (_Float16)y.z, (_Float16)y.w};
            float4 u = *(const float4*)(qr + d0);
            float4 v = *(const float4*)(qr + d0 + 4);
            aq[rb][ks] = (f16x8){(_Float16)u.x, (_Float16)u.y, (_Float16)u.z, (_Float16)u.w,
                                 (_Float16)v.x, (_Float16)v.y, (_Float16)v.z, (_Float16)v.w};
        }
    }

    float est[8] = {0.f, 0.f, 0.f, 0.f, 0.f, 0.f, 0.f, 0.f};

    LOADB(bB, 1);
    DO_CHUNK(0, bA); LOADB(bA, 2);
    DO_CHUNK(1, bB); LOADB(bB, 3);
    DO_CHUNK(2, bA); LOADB(bA, 4);
    DO_CHUNK(3, bB); LOADB(bB, 5);
    DO_CHUNK(4, bA); LOADB(bA, 6);
    DO_CHUNK(5, bB); LOADB(bB, 7);
    DO_CHUNK(6, bA);
    DO_CHUNK(7, bB);

    // ---- reduce est over the 16 proj-lanes ----
    #pragma unroll
    for (int rb = 0; rb < 2; ++rb) {
        #pragma unroll
        for (int r = 0; r < 4; ++r) {
            float e = est[rb * 4 + r];
            e += __shfl_xor(e, 1);
            e += __shfl_xor(e, 2);
            e += __shfl_xor(e, 4);
            e += __shfl_xor(e, 8);
            if (m == 0) est_s[wv * 32 + rb * 16 + quad * 4 + r] = DEQ * e;
        }
    }
    __syncthreads();

    // ---- refine: per-THREAD exact fp64 dot for near-zero k_proj candidates ----
    int nc = qn < QCAP ? qn : QCAP;
    for (int i = tid; i < nc; i += 256) {
        uint32_t mm = qmeta[i];
        int tl = mm & 255;
        int p  = (mm >> 8) & 255;
        int sf = (mm >> 16) & 1;
        const float4* kr = (const float4*)(kg + (tok0 + tl) * DIM);
        const float4* sr = (const float4*)(Sg + (long)p * DIM);
        double acc = 0.0;
        #pragma unroll 8
        for (int jj = 0; jj < 32; ++jj) {
            float4 ka = kr[jj], sa = sr[jj];
            acc += (double)ka.x * (double)sa.x + (double)ka.y * (double)sa.y
                 + (double)ka.z * (double)sa.z + (double)ka.w * (double)sa.w;
        }
        int st = (acc > 0.0) ? 1 : 0;
        if (st != sf) atomicAdd(&est_s[tl], -2.f * qdlt[i]);
    }
    __syncthreads();

    if (tid < TPB) out[tok0 + tid] = est_s[tid];
}

extern "C" void kernel_launch(void* const* d_in, const int* in_sizes, int n_in,
                              void* d_out, int out_size, void* d_ws, size_t ws_size,
                              hipStream_t stream) {
    const float* q = (const float*)d_in[0];
    const float* k = (const float*)d_in[1];
    const float* S = (const float*)d_in[2];
    float* out = (float*)d_out;
    _Float16* ws = (_Float16*)d_ws;
    hipLaunchKernelGGL(qjl_prep, dim3(16), dim3(256), 0, stream, S, ws);
    int nblocks = out_size / TPB;   // 262144 / 128 = 2048
    hipLaunchKernelGGL(qjl_main, dim3(nblocks), dim3(256), 0, stream, q, k, S, ws, out);
}

// Round 5
// 324.460 us; speedup vs baseline: 1.3884x; 1.1874x over previous
//
#include <hip/hip_runtime.h>
#include <stdint.h>

#define DIM 128
#define NPROJ 256
#define TPB 128                    // tokens per block (4 waves x 32)
#define TAU 0.016f                 // refine threshold on |k_proj_f16| (~7 sigma of f16 dot err)
#define QCAP 512
#define DEQ 0.004895758348888673f  // sqrt(pi/2)/256

typedef _Float16 f16x8 __attribute__((ext_vector_type(8)));
typedef float f32x4 __attribute__((ext_vector_type(4)));

// ---- prep: S fp32 -> f16 B-fragments, pre-swizzled into MFMA lane order ----
// frag fid = c*8 + ks*2 + f; lane l holds B[n=p][k=d]: p = c*32 + f*16 + (l&15),
// d = ks*32 + (l>>4)*8 + j
__global__ __launch_bounds__(256) void qjl_prep(const float* __restrict__ Sg,
                                                _Float16* __restrict__ ws) {
    int t = blockIdx.x * 256 + threadIdx.x;   // 0..4095
    int lane = t & 63, fid = t >> 6;          // 64 frags
    int f = fid & 1, ks = (fid >> 1) & 3, c = fid >> 3;
    int p = c * 32 + f * 16 + (lane & 15);
    int d0 = ks * 32 + (lane >> 4) * 8;
    const float4* s4 = (const float4*)(Sg + p * DIM + d0);
    float4 a = s4[0], b = s4[1];
    f16x8 h = {(_Float16)a.x, (_Float16)a.y, (_Float16)a.z, (_Float16)a.w,
               (_Float16)b.x, (_Float16)b.y, (_Float16)b.z, (_Float16)b.w};
    *(f16x8*)(ws + (size_t)fid * 512 + lane * 8) = h;
}

// load the 4 B-frags of (chunk C, 16-proj tile T) into named buffer
#define LOADT(buf, C, T)                                                             \
    { _Pragma("unroll")                                                              \
      for (int ks = 0; ks < 4; ++ks)                                                 \
          buf[ks] = *(const f16x8*)(ws + (size_t)((C) * 8 + ks * 2 + (T)) * 512 + lane * 8); }

// A fragments (either K or Q rows) fp32 -> f16 into af[2][4]
#define LOADA(src)                                                                   \
    { _Pragma("unroll")                                                              \
      for (int rb = 0; rb < 2; ++rb) {                                               \
          const float* rp = (src) + (tok0 + wv * 32 + rb * 16 + m) * DIM;            \
          _Pragma("unroll")                                                          \
          for (int ks = 0; ks < 4; ++ks) {                                           \
              int d0 = ks * 32 + quad * 8;                                           \
              float4 x = *(const float4*)(rp + d0);                                  \
              float4 y = *(const float4*)(rp + d0 + 4);                              \
              af[rb][ks] = (f16x8){(_Float16)x.x, (_Float16)x.y, (_Float16)x.z, (_Float16)x.w, \
                                   (_Float16)y.x, (_Float16)y.y, (_Float16)y.z, (_Float16)y.w}; } } }

// K pass step: signs -> sb0/sb1 bits, near-zero -> candidate queue
#define K_STEP(C, T, buf)                                                            \
    { f32x4 a0 = {0,0,0,0}, a1 = {0,0,0,0};                                          \
      _Pragma("unroll")                                                              \
      for (int ks = 0; ks < 4; ++ks) {                                               \
          a0 = __builtin_amdgcn_mfma_f32_16x16x32_f16(af[0][ks], buf[ks], a0, 0,0,0);\
          a1 = __builtin_amdgcn_mfma_f32_16x16x32_f16(af[1][ks], buf[ks], a1, 0,0,0);\
      }                                                                              \
      _Pragma("unroll")                                                              \
      for (int r = 0; r < 4; ++r) {                                                  \
          const int bidx = (C) * 8 + (T) * 4 + r;                                    \
          float kv0 = a0[r], kv1 = a1[r];                                            \
          sb0[bidx >> 5] |= (kv0 > 0.f) ? (1u << (bidx & 31)) : 0u;                  \
          sb1[bidx >> 5] |= (kv1 > 0.f) ? (1u << (bidx & 31)) : 0u;                  \
          if (__builtin_expect(fabsf(kv0) < TAU, 0)) {                               \
              int idx = atomicAdd(&qn, 1);                                           \
              if (idx < QCAP) qmeta[idx] = (uint32_t)(wv * 32 + quad * 4 + r)        \
                  | ((uint32_t)((C) * 32 + (T) * 16 + m) << 8)                       \
                  | ((kv0 > 0.f ? 1u : 0u) << 16);                                   \
          }                                                                          \
          if (__builtin_expect(fabsf(kv1) < TAU, 0)) {                               \
              int idx = atomicAdd(&qn, 1);                                           \
              if (idx < QCAP) qmeta[idx] = (uint32_t)(wv * 32 + 16 + quad * 4 + r)   \
                  | ((uint32_t)((C) * 32 + (T) * 16 + m) << 8)                       \
                  | ((kv1 > 0.f ? 1u : 0u) << 16);                                   \
          } } }

// Q pass step: est += q_proj * stored sign
#define Q_STEP(C, T, buf)                                                            \
    { f32x4 a0 = {0,0,0,0}, a1 = {0,0,0,0};                                          \
      _Pragma("unroll")                                                              \
      for (int ks = 0; ks < 4; ++ks) {                                               \
          a0 = __builtin_amdgcn_mfma_f32_16x16x32_f16(af[0][ks], buf[ks], a0, 0,0,0);\
          a1 = __builtin_amdgcn_mfma_f32_16x16x32_f16(af[1][ks], buf[ks], a1, 0,0,0);\
      }                                                                              \
      _Pragma("unroll")                                                              \
      for (int r = 0; r < 4; ++r) {                                                  \
          const int bidx = (C) * 8 + (T) * 4 + r;                                    \
          est[r]     += ((sb0[bidx >> 5] >> (bidx & 31)) & 1u) ? a0[r] : -a0[r];     \
          est[4 + r] += ((sb1[bidx >> 5] >> (bidx & 31)) & 1u) ? a1[r] : -a1[r]; } }

__global__ __launch_bounds__(256, 2) void qjl_main(
    const float* __restrict__ qg, const float* __restrict__ kg,
    const float* __restrict__ Sg, const _Float16* __restrict__ ws,
    float* __restrict__ out)
{
    __shared__ float    est_s[TPB];
    __shared__ uint32_t qmeta[QCAP];
    __shared__ int      qn;

    const int tid = threadIdx.x, lane = tid & 63, wv = tid >> 6;
    const int m = lane & 15, quad = lane >> 4;
    const long tok0 = (long)blockIdx.x * TPB;
    if (tid == 0) qn = 0;
    __syncthreads();

    f16x8 af[2][4];            // A fragments (K rows in pass 1, Q rows in pass 2)
    f16x8 tA[4], tB[4];        // B half-chunk double buffer
    uint32_t sb0[2] = {0u, 0u}, sb1[2] = {0u, 0u};   // 128 sign bits / lane

    // ================= K pass: signs + candidates =================
    LOADT(tA, 0, 0);
    LOADA(kg);
    LOADT(tB, 0, 1);
    K_STEP(0, 0, tA); LOADT(tA, 1, 0);
    K_STEP(0, 1, tB); LOADT(tB, 1, 1);
    K_STEP(1, 0, tA); LOADT(tA, 2, 0);
    K_STEP(1, 1, tB); LOADT(tB, 2, 1);
    K_STEP(2, 0, tA); LOADT(tA, 3, 0);
    K_STEP(2, 1, tB); LOADT(tB, 3, 1);
    K_STEP(3, 0, tA); LOADT(tA, 4, 0);
    K_STEP(3, 1, tB); LOADT(tB, 4, 1);
    K_STEP(4, 0, tA); LOADT(tA, 5, 0);
    K_STEP(4, 1, tB); LOADT(tB, 5, 1);
    K_STEP(5, 0, tA); LOADT(tA, 6, 0);
    K_STEP(5, 1, tB); LOADT(tB, 6, 1);
    K_STEP(6, 0, tA); LOADT(tA, 7, 0);
    K_STEP(6, 1, tB); LOADT(tB, 7, 1);
    K_STEP(7, 0, tA);
    K_STEP(7, 1, tB);

    // ================= Q pass: estimate =================
    float est[8] = {0.f, 0.f, 0.f, 0.f, 0.f, 0.f, 0.f, 0.f};
    LOADT(tA, 0, 0);
    LOADA(qg);
    LOADT(tB, 0, 1);
    Q_STEP(0, 0, tA); LOADT(tA, 1, 0);
    Q_STEP(0, 1, tB); LOADT(tB, 1, 1);
    Q_STEP(1, 0, tA); LOADT(tA, 2, 0);
    Q_STEP(1, 1, tB); LOADT(tB, 2, 1);
    Q_STEP(2, 0, tA); LOADT(tA, 3, 0);
    Q_STEP(2, 1, tB); LOADT(tB, 3, 1);
    Q_STEP(3, 0, tA); LOADT(tA, 4, 0);
    Q_STEP(3, 1, tB); LOADT(tB, 4, 1);
    Q_STEP(4, 0, tA); LOADT(tA, 5, 0);
    Q_STEP(4, 1, tB); LOADT(tB, 5, 1);
    Q_STEP(5, 0, tA); LOADT(tA, 6, 0);
    Q_STEP(5, 1, tB); LOADT(tB, 6, 1);
    Q_STEP(6, 0, tA); LOADT(tA, 7, 0);
    Q_STEP(6, 1, tB); LOADT(tB, 7, 1);
    Q_STEP(7, 0, tA);
    Q_STEP(7, 1, tB);

    // ---- reduce est over the 16 proj-lanes ----
    #pragma unroll
    for (int rb = 0; rb < 2; ++rb) {
        #pragma unroll
        for (int r = 0; r < 4; ++r) {
            float e = est[rb * 4 + r];
            e += __shfl_xor(e, 1);
            e += __shfl_xor(e, 2);
            e += __shfl_xor(e, 4);
            e += __shfl_xor(e, 8);
            if (m == 0) est_s[wv * 32 + rb * 16 + quad * 4 + r] = DEQ * e;
        }
    }
    __syncthreads();

    // ---- refine: per-thread exact fp64 dots; patch est on sign flips ----
    int nc = qn < QCAP ? qn : QCAP;
    for (int i = tid; i < nc; i += 256) {
        uint32_t mm = qmeta[i];
        int tl = mm & 255;
        int p  = (mm >> 8) & 255;
        int sf = (mm >> 16) & 1;
        const float4* kr = (const float4*)(kg + (tok0 + tl) * DIM);
        const float4* qr = (const float4*)(qg + (tok0 + tl) * DIM);
        const float4* sr = (const float4*)(Sg + (long)p * DIM);
        double dk = 0.0, dq = 0.0;
        #pragma unroll 8
        for (int j = 0; j < 32; ++j) {
            float4 kv4 = kr[j], qv4 = qr[j], sv4 = sr[j];
            dk += (double)kv4.x * (double)sv4.x + (double)kv4.y * (double)sv4.y
                + (double)kv4.z * (double)sv4.z + (double)kv4.w * (double)sv4.w;
            dq += (double)qv4.x * (double)sv4.x + (double)qv4.y * (double)sv4.y
                + (double)qv4.z * (double)sv4.z + (double)qv4.w * (double)sv4.w;
        }
        int st = (dk > 0.0) ? 1 : 0;
        if (st != sf) {
            float sg = sf ? 1.f : -1.f;
            atomicAdd(&est_s[tl], -2.f * DEQ * (float)dq * sg);
        }
    }
    __syncthreads();

    if (tid < TPB) out[tok0 + tid] = est_s[tid];
}

extern "C" void kernel_launch(void* const* d_in, const int* in_sizes, int n_in,
                              void* d_out, int out_size, void* d_ws, size_t ws_size,
                              hipStream_t stream) {
    const float* q = (const float*)d_in[0];
    const float* k = (const float*)d_in[1];
    const float* S = (const float*)d_in[2];
    float* out = (float*)d_out;
    _Float16* ws = (_Float16*)d_ws;
    hipLaunchKernelGGL(qjl_prep, dim3(16), dim3(256), 0, stream, S, ws);
    int nblocks = out_size / TPB;   // 262144 / 128 = 2048
    hipLaunchKernelGGL(qjl_main, dim3(nblocks), dim3(256), 0, stream, q, k, S, ws, out);
}